// Round 12
// baseline (409.405 us; speedup 1.0000x reference)
//
#include <hip/hip_runtime.h>
#include <math.h>

#define NEG_SLOPE 0.2f

__device__ inline float lrelu(float x) { return x > 0.f ? x : NEG_SLOPE * x; }

typedef __attribute__((ext_vector_type(8))) _Float16 f16x8;
typedef __attribute__((ext_vector_type(4))) float f32x4;
typedef __attribute__((ext_vector_type(4))) _Float16 h16x4;

// ==== fused: edge-count histogram + weight transpose/convert (block-partitioned)
__global__ void count_conv_k(const int* __restrict__ dst, int* __restrict__ counts,
                             const float* __restrict__ W1, const float* __restrict__ W2,
                             _Float16* __restrict__ BT1, _Float16* __restrict__ BT2,
                             int E, int Nn, int NBc)
{
    int b = blockIdx.x;
    if (b < NBc) {
        int e = b * 256 + threadIdx.x;
        if (e >= E + Nn) return;
        int d = (e < E) ? dst[e] : (e - E);
        atomicAdd(&counts[d], 1);
    } else {
        int i = (b - NBc) * 256 + threadIdx.x;       // 0..65535
        if (i < 32768) {
            int n = i >> 7, k = i & 127;             // K=128, N=256
            BT1[(size_t)n * 128 + k] = (_Float16)W1[(size_t)k * 256 + n];
        } else {
            int idx = i - 32768;
            int n = idx >> 8, k = idx & 255;         // K=256, N=128
            BT2[(size_t)n * 256 + k] = (_Float16)W2[(size_t)k * 128 + n];
        }
    }
}

__global__ void scan1_k(const int* __restrict__ counts, int* __restrict__ partial,
                        int* __restrict__ bsum, int Nn)
{
    __shared__ int sh[256];
    int i = blockIdx.x * 256 + threadIdx.x;
    int v = (i < Nn) ? counts[i] : 0;
    sh[threadIdx.x] = v;
    __syncthreads();
#pragma unroll
    for (int o = 1; o < 256; o <<= 1) {
        int t = (threadIdx.x >= o) ? sh[threadIdx.x - o] : 0;
        __syncthreads();
        sh[threadIdx.x] += t;
        __syncthreads();
    }
    if (i < Nn) partial[i] = sh[threadIdx.x] - v;
    if (threadIdx.x == 255) bsum[blockIdx.x] = sh[255];
}

// scan of block sums (done redundantly per block) + rowptr/cursor emit
__global__ void scan3_k(const int* __restrict__ partial, const int* __restrict__ bsum,
                        int* __restrict__ rowptr, int* __restrict__ cursor,
                        int Nn, int ET, int nb)
{
    __shared__ int sh[256];
    __shared__ int ex[256];
    int t = threadIdx.x;
    int v = (t < nb) ? bsum[t] : 0;
    sh[t] = v;
    __syncthreads();
#pragma unroll
    for (int o = 1; o < 256; o <<= 1) {
        int tmp = (t >= o) ? sh[t - o] : 0;
        __syncthreads();
        sh[t] += tmp;
        __syncthreads();
    }
    ex[t] = sh[t] - v;                 // exclusive
    __syncthreads();
    int i = blockIdx.x * 256 + t;
    if (i < Nn) {
        int r = partial[i] + ex[i >> 8];
        rowptr[i] = r;
        cursor[i] = r;
    }
    if (i == Nn) rowptr[Nn] = ET;
}

__global__ void build_k(const int* __restrict__ src, const int* __restrict__ dst,
                        int* __restrict__ cursor, int* __restrict__ esrc, int E, int Nn)
{
    int e = blockIdx.x * blockDim.x + threadIdx.x;
    if (e >= E + Nn) return;
    int s, d;
    if (e < E) { s = src[e]; d = dst[e]; } else { s = e - E; d = s; }
    int pos = atomicAdd(&cursor[d], 1);
    esrc[pos] = s;
}

// ---- Fused fp16 MFMA GEMM + fp16 out + attention logits ----------------------
// A: fp32 or fp16 row-major [M][K]; BT: [N][K] fp16; B frags loaded直接 from
// global (W is L1/L2-resident). Epilogue: HB fp16 + logits (H=4 direct, H=1 atomic).
template<int N, int K, int H, typename AT>
__launch_bounds__(256)
__global__ void gemm_fused(const AT* __restrict__ A, const _Float16* __restrict__ BT,
                           _Float16* __restrict__ HB, const float* __restrict__ att_s,
                           const float* __restrict__ att_d, float* __restrict__ aS,
                           float* __restrict__ aD, int M)
{
    constexpr int ITERS = K / 32;
    constexpr int WN = N / 4;
    constexpr int NT = WN / 16;
    __shared__ _Float16 As[64 * 40] __attribute__((aligned(16)));
    const int t = threadIdx.x;
    const int wave = t >> 6, lane = t & 63;
    const int quad = lane >> 4, l15 = lane & 15;
    const int rowBase = blockIdx.x * 64;

    f32x4 acc[4][NT];
#pragma unroll
    for (int mi = 0; mi < 4; ++mi)
#pragma unroll
        for (int ni = 0; ni < NT; ++ni)
            acc[mi][ni] = (f32x4){0.f, 0.f, 0.f, 0.f};

    const int ar = t >> 2;             // A-stage row 0..63
    const int ak = (t & 3) << 3;       // A-stage k seg 0,8,16,24

    for (int it = 0; it < ITERS; ++it) {
        // ---- stage A into LDS (fp32 converts; fp16 copies)
        {
            int gr = rowBase + ar;
            f16x8 hv = (f16x8){0, 0, 0, 0, 0, 0, 0, 0};
            if (gr < M) {
                if constexpr (sizeof(AT) == 4) {
                    const float* ap = (const float*)A + (size_t)gr * K + it * 32 + ak;
                    float4 v0 = *(const float4*)ap;
                    float4 v1 = *(const float4*)(ap + 4);
                    hv[0] = (_Float16)v0.x; hv[1] = (_Float16)v0.y;
                    hv[2] = (_Float16)v0.z; hv[3] = (_Float16)v0.w;
                    hv[4] = (_Float16)v1.x; hv[5] = (_Float16)v1.y;
                    hv[6] = (_Float16)v1.z; hv[7] = (_Float16)v1.w;
                } else {
                    hv = *(const f16x8*)((const _Float16*)A + (size_t)gr * K + it * 32 + ak);
                }
            }
            *(f16x8*)&As[ar * 40 + ak] = hv;
        }
        __syncthreads();
        f16x8 af[4], bfr[NT];
#pragma unroll
        for (int mi = 0; mi < 4; ++mi)
            af[mi] = *(const f16x8*)&As[(mi * 16 + l15) * 40 + quad * 8];
#pragma unroll
        for (int ni = 0; ni < NT; ++ni)
            bfr[ni] = *(const f16x8*)&BT[(size_t)(wave * WN + ni * 16 + l15) * K + it * 32 + quad * 8];
#pragma unroll
        for (int mi = 0; mi < 4; ++mi)
#pragma unroll
            for (int ni = 0; ni < NT; ++ni)
                acc[mi][ni] = __builtin_amdgcn_mfma_f32_16x16x32_f16(
                    af[mi], bfr[ni], acc[mi][ni], 0, 0, 0);
        __syncthreads();
    }
    // ---- epilogue: fp16 store + logits. D layout col=lane&15, row=quad*4+reg
    float asv[NT], adv[NT];
#pragma unroll
    for (int ni = 0; ni < NT; ++ni) {
        int col = wave * WN + ni * 16 + l15;
        asv[ni] = att_s[col];
        adv[ni] = att_d[col];
    }
#pragma unroll
    for (int mi = 0; mi < 4; ++mi) {
#pragma unroll
        for (int r = 0; r < 4; ++r) {
            int row = rowBase + mi * 16 + quad * 4 + r;
            bool ok = row < M;
            float ss = 0.f, sd = 0.f;
#pragma unroll
            for (int ni = 0; ni < NT; ++ni) {
                float v = acc[mi][ni][r];
                ss += v * asv[ni];
                sd += v * adv[ni];
                if (ok)
                    HB[(size_t)row * N + wave * WN + ni * 16 + l15] = (_Float16)v;
            }
#pragma unroll
            for (int off = 8; off > 0; off >>= 1) {
                ss += __shfl_xor(ss, off);
                sd += __shfl_xor(sd, off);
            }
            if (ok && l15 == 0) {
                if (H == 4) {
                    aS[row * 4 + wave] = ss;
                    aD[row * 4 + wave] = sd;
                } else {
                    atomicAdd(&aS[row], ss);
                    atomicAdd(&aD[row], sd);
                }
            }
        }
    }
}

// ===== gather layer 1, fp16 h, online softmax, 8-edge unroll; fp16 out =========
__global__ void gather1_k(const int* __restrict__ rp, const int* __restrict__ esrc,
                          const _Float16* __restrict__ hb, const float* __restrict__ aS,
                          const float* __restrict__ aD, const float* __restrict__ bias,
                          _Float16* __restrict__ out, int Nn)
{
    int d = blockIdx.x * 4 + (threadIdx.x >> 6);
    int lane = threadIdx.x & 63;
    if (d >= Nn) return;
    int c4 = lane << 2;
    int head = lane >> 4;
    int p0 = rp[d], p1 = rp[d + 1];
    float adh = aD[d * 4 + head];
    const float* aSh = aS + head;
    float m = -1e30f, den = 0.f;
    float ax = 0.f, ay = 0.f, az = 0.f, aw = 0.f;
    int p = p0;
    for (; p + 8 <= p1; p += 8) {
        int s[8];
        float l[8];
#pragma unroll
        for (int j = 0; j < 8; ++j) s[j] = esrc[p + j];
#pragma unroll
        for (int j = 0; j < 8; ++j) l[j] = lrelu(aSh[s[j] * 4] + adh);
        float lm = l[0];
#pragma unroll
        for (int j = 1; j < 8; ++j) lm = fmaxf(lm, l[j]);
        if (lm > m) {
            float r = __expf(m - lm);
            ax *= r; ay *= r; az *= r; aw *= r; den *= r;
            m = lm;
        }
        h16x4 v[8];
#pragma unroll
        for (int j = 0; j < 8; ++j) v[j] = *(const h16x4*)&hb[(size_t)s[j] * 256 + c4];
#pragma unroll
        for (int j = 0; j < 8; ++j) {
            float w = __expf(l[j] - m);
            den += w;
            ax += (float)v[j][0] * w;
            ay += (float)v[j][1] * w;
            az += (float)v[j][2] * w;
            aw += (float)v[j][3] * w;
        }
    }
    for (; p < p1; ++p) {
        int s0 = esrc[p];
        float l0 = lrelu(aSh[s0 * 4] + adh);
        if (l0 > m) {
            float r = __expf(m - l0);
            ax *= r; ay *= r; az *= r; aw *= r; den *= r;
            m = l0;
        }
        float w0 = __expf(l0 - m);
        den += w0;
        h16x4 v0 = *(const h16x4*)&hb[(size_t)s0 * 256 + c4];
        ax += (float)v0[0] * w0; ay += (float)v0[1] * w0;
        az += (float)v0[2] * w0; aw += (float)v0[3] * w0;
    }
    float inv = 1.f / (den + 1e-16f);
    float4 b4 = *(const float4*)&bias[c4];
    float rx = ax * inv + b4.x; rx = rx > 0.f ? rx : expm1f(rx);
    float ry = ay * inv + b4.y; ry = ry > 0.f ? ry : expm1f(ry);
    float rz = az * inv + b4.z; rz = rz > 0.f ? rz : expm1f(rz);
    float rw = aw * inv + b4.w; rw = rw > 0.f ? rw : expm1f(rw);
    h16x4 o;
    o[0] = (_Float16)rx; o[1] = (_Float16)ry;
    o[2] = (_Float16)rz; o[3] = (_Float16)rw;
    *(h16x4*)&out[(size_t)d * 256 + c4] = o;
}

// ===== gather layer 2, fp16 h, online softmax, half-waves; fp16 out ============
__global__ void gather2_k(const int* __restrict__ rp, const int* __restrict__ esrc,
                          const _Float16* __restrict__ hb, const float* __restrict__ aS,
                          const float* __restrict__ aD, _Float16* __restrict__ out, int Nn)
{
    int d = blockIdx.x * 4 + (threadIdx.x >> 6);
    int lane = threadIdx.x & 63;
    if (d >= Nn) return;
    int half = lane >> 5;
    int c4 = (lane & 31) << 2;
    int p0 = rp[d], p1 = rp[d + 1];
    float adh = aD[d];
    float m = -1e30f, den = 0.f;
    float ax = 0.f, ay = 0.f, az = 0.f, aw = 0.f;
    int p = p0 + half;
    for (; p + 6 < p1; p += 8) {
        int s[4];
        float l[4];
#pragma unroll
        for (int j = 0; j < 4; ++j) s[j] = esrc[p + 2 * j];
#pragma unroll
        for (int j = 0; j < 4; ++j) l[j] = lrelu(aS[s[j]] + adh);
        float lm = fmaxf(fmaxf(l[0], l[1]), fmaxf(l[2], l[3]));
        if (lm > m) {
            float r = __expf(m - lm);
            ax *= r; ay *= r; az *= r; aw *= r; den *= r;
            m = lm;
        }
        h16x4 v[4];
#pragma unroll
        for (int j = 0; j < 4; ++j) v[j] = *(const h16x4*)&hb[(size_t)s[j] * 128 + c4];
#pragma unroll
        for (int j = 0; j < 4; ++j) {
            float w = __expf(l[j] - m);
            den += w;
            ax += (float)v[j][0] * w;
            ay += (float)v[j][1] * w;
            az += (float)v[j][2] * w;
            aw += (float)v[j][3] * w;
        }
    }
    for (; p < p1; p += 2) {
        int s0 = esrc[p];
        float l0 = lrelu(aS[s0] + adh);
        if (l0 > m) {
            float r = __expf(m - l0);
            ax *= r; ay *= r; az *= r; aw *= r; den *= r;
            m = l0;
        }
        float w0 = __expf(l0 - m);
        den += w0;
        h16x4 v0 = *(const h16x4*)&hb[(size_t)s0 * 128 + c4];
        ax += (float)v0[0] * w0; ay += (float)v0[1] * w0;
        az += (float)v0[2] * w0; aw += (float)v0[3] * w0;
    }
    // merge halves: rescale to common max, then sum
    float mo = __shfl_xor(m, 32);
    float mm = fmaxf(m, mo);
    float fsc = __expf(m - mm);
    ax *= fsc; ay *= fsc; az *= fsc; aw *= fsc; den *= fsc;
    ax += __shfl_xor(ax, 32);
    ay += __shfl_xor(ay, 32);
    az += __shfl_xor(az, 32);
    aw += __shfl_xor(aw, 32);
    den += __shfl_xor(den, 32);
    float inv = 1.f / (den + 1e-16f);
    if (half == 0) {
        h16x4 o;
        o[0] = (_Float16)(ax * inv); o[1] = (_Float16)(ay * inv);
        o[2] = (_Float16)(az * inv); o[3] = (_Float16)(aw * inv);
        *(h16x4*)&out[(size_t)d * 128 + c4] = o;
    }
}

// batch is sorted; per-block run-length accumulate then atomicAdd per graph run
__global__ void pool_k(const _Float16* __restrict__ o2, const float* __restrict__ b2,
                       const int* __restrict__ batch, float* __restrict__ sums, int Nn, int C)
{
    int c = threadIdx.x;               // C = 128
    int n0 = blockIdx.x * 64;
    int n1 = min(n0 + 64, Nn);
    float local = 0.f;
    int gcur = batch[n0];
    float bc = b2[c];
    for (int n = n0; n < n1; ++n) {
        int g = batch[n];
        if (g != gcur) {
            atomicAdd(&sums[gcur * C + c], local);
            local = 0.f;
            gcur = g;
        }
        float v = (float)o2[(size_t)n * C + c] + bc;
        local += v > 0.f ? v : expm1f(v);
    }
    atomicAdd(&sums[gcur * C + c], local);
}

__global__ void final_k(const float* __restrict__ sums, const int* __restrict__ batch,
                        const float* __restrict__ lin_w, const float* __restrict__ lin_b,
                        float* __restrict__ out, int Nn, int G, int C, int NC)
{
    __shared__ float inv[64];
    int t = threadIdx.x;
    if (t < G) {
        int lo = 0, hi = Nn;
        while (lo < hi) { int mid = (lo + hi) >> 1; if (batch[mid] < t) lo = mid + 1; else hi = mid; }
        int lb = lo;
        lo = 0; hi = Nn;
        while (lo < hi) { int mid = (lo + hi) >> 1; if (batch[mid] < t + 1) lo = mid + 1; else hi = mid; }
        int cnt = lo - lb;
        inv[t] = 1.f / fmaxf((float)cnt, 1.f);
    }
    __syncthreads();
    if (t < G * NC) {
        int g = t / NC, k = t % NC;
        float acc = 0.f;
        for (int c = 0; c < C; ++c) acc += sums[g * C + c] * lin_w[c * NC + k];
        out[t] = acc * inv[g] + lin_b[k];
    }
}

extern "C" void kernel_launch(void* const* d_in, const int* in_sizes, int n_in,
                              void* d_out, int out_size, void* d_ws, size_t ws_size,
                              hipStream_t stream)
{
    const float* x      = (const float*)d_in[0];
    const int*   eidx   = (const int*)d_in[1];
    const int*   batch  = (const int*)d_in[2];
    const float* W1     = (const float*)d_in[3];
    const float* att_s1 = (const float*)d_in[4];
    const float* att_d1 = (const float*)d_in[5];
    const float* b1     = (const float*)d_in[6];
    const float* W2     = (const float*)d_in[7];
    const float* att_s2 = (const float*)d_in[8];
    const float* att_d2 = (const float*)d_in[9];
    const float* b2     = (const float*)d_in[10];
    const float* lin_w  = (const float*)d_in[11];
    const float* lin_b  = (const float*)d_in[12];

    const int Nn  = in_sizes[2];         // 50000
    const int E   = in_sizes[1] / 2;     // 800000
    const int H1_ = 4, C1_ = 64, C2_ = 128, G = 32, NC = 5;
    const int D1 = H1_ * C1_;            // 256
    const int ET = E + Nn;

    const int* srcp = eidx;
    const int* dstp = eidx + E;

    float* ws = (float*)d_ws;
    size_t off = 0;
    // --- zero-init region (one memset): counts | aS2 | aD2 | sums ---
    int*   counts = (int*)ws;            off += Nn;
    float* aS2    = ws + off;            off += Nn;
    float* aD2    = ws + off;            off += Nn;
    float* sums   = ws + off;            off += (size_t)G * C2_;
    // --- rest ---
    float* aS1 = ws + off;               off += (size_t)Nn * H1_;
    float* aD1 = ws + off;               off += (size_t)Nn * H1_;
    _Float16* BT1 = (_Float16*)(ws + off); off += 16384;           // [256][128] fp16
    _Float16* BT2 = (_Float16*)(ws + off); off += 16384;           // [128][256] fp16
    _Float16* hb1 = (_Float16*)(ws + off); off += (size_t)Nn * 128; // [Nn][256] fp16
    _Float16* o1h = (_Float16*)(ws + off); off += (size_t)Nn * 128; // [Nn][256] fp16
    _Float16* hb2 = (_Float16*)(ws + off); off += (size_t)Nn * 64;  // [Nn][128] fp16
    _Float16* o2h = (_Float16*)(ws + off); off += (size_t)Nn * 64;  // [Nn][128] fp16
    int* iws    = (int*)(ws + off);
    int* partial= iws;                    // Nn
    int* rowptr = iws + Nn;               // Nn+1
    int* cursor = iws + 2 * Nn + 1;       // Nn
    int* bsum   = iws + 3 * Nn + 1;       // <=256
    int* esrc   = iws + 3 * Nn + 1 + 256; // ET

    const int NB  = (Nn + 255) / 256;
    const int NBc = (ET + 255) / 256;
    const int GB  = (Nn + 63) / 64;

    // ---------------- zero-init + CSR build + weight convert ----------------
    hipMemsetAsync(counts, 0, (size_t)(3 * Nn + G * C2_) * 4, stream);
    count_conv_k<<<NBc + 256, 256, 0, stream>>>(dstp, counts, W1, W2, BT1, BT2, E, Nn, NBc);
    scan1_k<<<NB, 256, 0, stream>>>(counts, partial, bsum, Nn);
    scan3_k<<<(Nn + 256) / 256, 256, 0, stream>>>(partial, bsum, rowptr, cursor, Nn, ET, NB);
    build_k<<<(ET + 255) / 256, 256, 0, stream>>>(srcp, dstp, cursor, esrc, E, Nn);

    // ---------------- layer 1: fp16 GEMM + fp16 out + logits fused ----------------
    gemm_fused<256, 128, 4, float><<<GB, 256, 0, stream>>>(x, BT1, hb1, att_s1, att_d1,
                                                           aS1, aD1, Nn);
    gather1_k<<<(Nn + 3) / 4, 256, 0, stream>>>(rowptr, esrc, hb1, aS1, aD1, b1, o1h, Nn);

    // ---------------- layer 2: fp16 GEMM (fp16 A) + logits fused ----------------
    gemm_fused<128, 256, 1, _Float16><<<GB, 256, 0, stream>>>(o1h, BT2, hb2, att_s2, att_d2,
                                                              aS2, aD2, Nn);
    gather2_k<<<(Nn + 3) / 4, 256, 0, stream>>>(rowptr, esrc, hb2, aS2, aD2, o2h, Nn);

    // ---------------- pool + classifier ----------------
    pool_k<<<GB, C2_, 0, stream>>>(o2h, b2, batch, sums, Nn, C2_);
    final_k<<<1, 256, 0, stream>>>(sums, batch, lin_w, lin_b, (float*)d_out, Nn, G, C2_, NC);
}